// Round 1
// baseline (1418.525 us; speedup 1.0000x reference)
//
#include <hip/hip_runtime.h>

#define L_T 512
#define BATCH 1024
#define LB (L_T*BATCH)

typedef short bf16x8 __attribute__((ext_vector_type(8)));
typedef short bf16x4 __attribute__((ext_vector_type(4)));
typedef float f32x4 __attribute__((ext_vector_type(4)));
typedef unsigned short u16;

#define MFMA_B16(a,b,c) __builtin_amdgcn_mfma_f32_16x16x32_bf16((a),(b),(c),0,0,0)

__device__ __forceinline__ short f2bs(float f){
  union{float f; unsigned u;} c; c.f=f;
  unsigned r = (c.u + 0x7FFFu + ((c.u>>16)&1u)) >> 16;
  return (short)r;
}

__device__ __forceinline__ float sigmoidf_(float x){ return 1.0f/(1.0f + __expf(-x)); }
// tanh via 1 - 2/(1+e^{2x}); saturates correctly at +-inf without NaN
__device__ __forceinline__ float tanhf_(float x){ return 1.0f - 2.0f/(1.0f + __expf(2.0f*x)); }

__device__ __forceinline__ void store8(u16* d, float4 a, float4 b){
  bf16x8 v;
  v[0]=f2bs(a.x); v[1]=f2bs(a.y); v[2]=f2bs(a.z); v[3]=f2bs(a.w);
  v[4]=f2bs(b.x); v[5]=f2bs(b.y); v[6]=f2bs(b.z); v[7]=f2bs(b.w);
  *(bf16x8*)d = v;
}

__device__ __forceinline__ bf16x8 bfrag_f32(const float* p){
  float4 a = *(const float4*)p;
  float4 b = *(const float4*)(p+4);
  bf16x8 v;
  v[0]=f2bs(a.x); v[1]=f2bs(a.y); v[2]=f2bs(a.z); v[3]=f2bs(a.w);
  v[4]=f2bs(b.x); v[5]=f2bs(b.y); v[6]=f2bs(b.z); v[7]=f2bs(b.w);
  return v;
}

// ---------------------------------------------------------------------------
// K1: two-layer preprocess  out = relu(relu(x@W1.T+b1)@W2.T+b2), Cin=32 fixed.
// One 64-row tile per block, 256 threads (4 waves x 16-row subtiles).
// ---------------------------------------------------------------------------
__global__ __launch_bounds__(256) void k_preprocess(
    const float* __restrict__ src,            // [LB][32]
    const float* __restrict__ W1,             // [64][32]
    const float* __restrict__ b1,             // [64]
    const float* __restrict__ W2,             // [64][64]
    const float* __restrict__ b2,             // [64]
    u16* __restrict__ out_b16, int ostride, int ooff,  // optional bf16 out
    float* __restrict__ out_f32)              // optional fp32 out [LB][64]
{
  __shared__ u16 in_t[64*40];
  __shared__ u16 w1t[64*40];
  __shared__ u16 w2t[64*88];
  __shared__ u16 t1t[64*88];
  __shared__ float lb1[64], lb2[64];

  const int t = threadIdx.x;
  const size_t row0 = (size_t)blockIdx.x * 64;

  {
    int r = t>>2, q = t&3;
    const float* ps = src + (row0 + r)*32 + q*8;
    store8(in_t + r*40 + q*8, *(const float4*)ps, *(const float4*)(ps+4));
    const float* pw = W1 + r*32 + q*8;
    store8(w1t + r*40 + q*8, *(const float4*)pw, *(const float4*)(pw+4));
    const float* pw2 = W2 + r*64 + q*16;
    store8(w2t + r*88 + q*16,     *(const float4*)pw2,     *(const float4*)(pw2+4));
    store8(w2t + r*88 + q*16 + 8, *(const float4*)(pw2+8), *(const float4*)(pw2+12));
    if (t < 64) lb1[t] = b1[t];
    else if (t < 128) lb2[t-64] = b2[t-64];
  }
  __syncthreads();

  const int lane = t & 63, wave = t >> 6;
  const int l15 = lane & 15, l4 = lane >> 4;
  const int rs = wave*16;

  // layer 1 (K=32: one k-chunk)
  {
    bf16x8 a = *(const bf16x8*)(in_t + (rs + l15)*40 + l4*8);
    #pragma unroll
    for (int ct = 0; ct < 4; ++ct) {
      f32x4 acc = {0.f,0.f,0.f,0.f};
      bf16x8 bw = *(const bf16x8*)(w1t + (ct*16 + l15)*40 + l4*8);
      acc = MFMA_B16(a, bw, acc);
      float bias = lb1[ct*16 + l15];
      #pragma unroll
      for (int i = 0; i < 4; ++i) {
        float v = fmaxf(acc[i] + bias, 0.f);
        t1t[(rs + l4*4 + i)*88 + ct*16 + l15] = (u16)f2bs(v);
      }
    }
  }
  __syncthreads();

  // layer 2 (K=64: two k-chunks)
  {
    bf16x8 a0 = *(const bf16x8*)(t1t + (rs + l15)*88 + l4*8);
    bf16x8 a1 = *(const bf16x8*)(t1t + (rs + l15)*88 + 32 + l4*8);
    #pragma unroll
    for (int ct = 0; ct < 4; ++ct) {
      f32x4 acc = {0.f,0.f,0.f,0.f};
      bf16x8 b0 = *(const bf16x8*)(w2t + (ct*16 + l15)*88 + l4*8);
      bf16x8 b1v = *(const bf16x8*)(w2t + (ct*16 + l15)*88 + 32 + l4*8);
      acc = MFMA_B16(a0, b0, acc);
      acc = MFMA_B16(a1, b1v, acc);
      float bias = lb2[ct*16 + l15];
      #pragma unroll
      for (int i = 0; i < 4; ++i) {
        float v = fmaxf(acc[i] + bias, 0.f);
        size_t gr = row0 + rs + l4*4 + i;
        int col = ct*16 + l15;
        if (out_b16) out_b16[gr*(size_t)ostride + ooff + col] = (u16)f2bs(v);
        if (out_f32) out_f32[gr*64 + col] = v;
      }
    }
  }
}

// ---------------------------------------------------------------------------
// K2: posterior DBlock + reparam sample.
// t = relu(d@W1.T+b1)*sigmoid(d@W2.T+b2); mu = t@Wmu.T+bmu; ls = t@Wls.T+bls;
// s = mu + exp(0.5 ls)*eps.  One 64-row tile per block.
// ---------------------------------------------------------------------------
__global__ __launch_bounds__(256) void k_posterior(
    const u16* __restrict__ dseq,             // [LB][64] bf16
    const float* __restrict__ eps,            // [LB][32]
    const float* __restrict__ W1, const float* __restrict__ b1,
    const float* __restrict__ W2, const float* __restrict__ b2,
    const float* __restrict__ Wmu, const float* __restrict__ bmu,
    const float* __restrict__ Wls, const float* __restrict__ bls,
    float* __restrict__ out_mu, float* __restrict__ out_ls, float* __restrict__ out_s)
{
  __shared__ u16 dt[64*88], w1t[64*88], w2t[64*88], tt[64*88];
  __shared__ u16 wmut[32*88], wlst[32*88];
  __shared__ float lb1[64], lb2[64], lbmu[32], lbls[32];

  const int t = threadIdx.x;
  const size_t row0 = (size_t)blockIdx.x * 64;

  {
    int r = t>>2, q = t&3;
    const u16* pd = dseq + (row0 + r)*64 + q*16;
    *(bf16x8*)(dt + r*88 + q*16)     = *(const bf16x8*)pd;
    *(bf16x8*)(dt + r*88 + q*16 + 8) = *(const bf16x8*)(pd + 8);
    const float* p1 = W1 + r*64 + q*16;
    store8(w1t + r*88 + q*16,     *(const float4*)p1,     *(const float4*)(p1+4));
    store8(w1t + r*88 + q*16 + 8, *(const float4*)(p1+8), *(const float4*)(p1+12));
    const float* p2 = W2 + r*64 + q*16;
    store8(w2t + r*88 + q*16,     *(const float4*)p2,     *(const float4*)(p2+4));
    store8(w2t + r*88 + q*16 + 8, *(const float4*)(p2+8), *(const float4*)(p2+12));
    if (t < 128) {
      int r2 = t>>2, q2 = t&3;   // r2 in 0..31
      const float* pm = Wmu + r2*64 + q2*16;
      store8(wmut + r2*88 + q2*16,     *(const float4*)pm,     *(const float4*)(pm+4));
      store8(wmut + r2*88 + q2*16 + 8, *(const float4*)(pm+8), *(const float4*)(pm+12));
    } else {
      int t2 = t - 128; int r2 = t2>>2, q2 = t2&3;
      const float* pl = Wls + r2*64 + q2*16;
      store8(wlst + r2*88 + q2*16,     *(const float4*)pl,     *(const float4*)(pl+4));
      store8(wlst + r2*88 + q2*16 + 8, *(const float4*)(pl+8), *(const float4*)(pl+12));
    }
    if (t < 64) lb1[t] = b1[t];
    else if (t < 128) lb2[t-64] = b2[t-64];
    else if (t < 160) lbmu[t-128] = bmu[t-128];
    else if (t < 192) lbls[t-160] = bls[t-160];
  }
  __syncthreads();

  const int lane = t & 63, wave = t >> 6;
  const int l15 = lane & 15, l4 = lane >> 4;
  const int rs = wave*16;

  // gated hidden
  {
    bf16x8 a0 = *(const bf16x8*)(dt + (rs + l15)*88 + l4*8);
    bf16x8 a1 = *(const bf16x8*)(dt + (rs + l15)*88 + 32 + l4*8);
    #pragma unroll
    for (int ct = 0; ct < 4; ++ct) {
      f32x4 c1 = {0.f,0.f,0.f,0.f}, c2 = {0.f,0.f,0.f,0.f};
      bf16x8 w1a = *(const bf16x8*)(w1t + (ct*16 + l15)*88 + l4*8);
      bf16x8 w1b = *(const bf16x8*)(w1t + (ct*16 + l15)*88 + 32 + l4*8);
      bf16x8 w2a = *(const bf16x8*)(w2t + (ct*16 + l15)*88 + l4*8);
      bf16x8 w2b = *(const bf16x8*)(w2t + (ct*16 + l15)*88 + 32 + l4*8);
      c1 = MFMA_B16(a0, w1a, c1); c1 = MFMA_B16(a1, w1b, c1);
      c2 = MFMA_B16(a0, w2a, c2); c2 = MFMA_B16(a1, w2b, c2);
      float bb1 = lb1[ct*16 + l15], bb2 = lb2[ct*16 + l15];
      #pragma unroll
      for (int i = 0; i < 4; ++i) {
        float tv = fmaxf(c1[i] + bb1, 0.f) * sigmoidf_(c2[i] + bb2);
        tt[(rs + l4*4 + i)*88 + ct*16 + l15] = (u16)f2bs(tv);
      }
    }
  }
  __syncthreads();

  // heads + sample
  {
    bf16x8 a0 = *(const bf16x8*)(tt + (rs + l15)*88 + l4*8);
    bf16x8 a1 = *(const bf16x8*)(tt + (rs + l15)*88 + 32 + l4*8);
    #pragma unroll
    for (int ct = 0; ct < 2; ++ct) {
      f32x4 cmu = {0.f,0.f,0.f,0.f}, cls = {0.f,0.f,0.f,0.f};
      bf16x8 wma = *(const bf16x8*)(wmut + (ct*16 + l15)*88 + l4*8);
      bf16x8 wmb = *(const bf16x8*)(wmut + (ct*16 + l15)*88 + 32 + l4*8);
      bf16x8 wla = *(const bf16x8*)(wlst + (ct*16 + l15)*88 + l4*8);
      bf16x8 wlb = *(const bf16x8*)(wlst + (ct*16 + l15)*88 + 32 + l4*8);
      cmu = MFMA_B16(a0, wma, cmu); cmu = MFMA_B16(a1, wmb, cmu);
      cls = MFMA_B16(a0, wla, cls); cls = MFMA_B16(a1, wlb, cls);
      float bm = lbmu[ct*16 + l15], bl = lbls[ct*16 + l15];
      #pragma unroll
      for (int i = 0; i < 4; ++i) {
        size_t R = row0 + rs + l4*4 + i;
        int col = ct*16 + l15;
        float mu = cmu[i] + bm;
        float ls = cls[i] + bl;
        float e  = eps[R*32 + col];
        float s  = mu + __expf(0.5f*ls)*e;
        out_mu[R*32 + col] = mu;
        out_ls[R*32 + col] = ls;
        out_s [R*32 + col] = s;
      }
    }
  }
}

// ---------------------------------------------------------------------------
// K3/K4: GRU scan. 64 blocks x 16 batch rows; 4 waves split the 192 gate cols
// as {w*16, 64+w*16, 128+w*16}. h kept fp32 in registers in MFMA C-layout;
// bf16 copy written to LDS each step for the A-fragment. Weights in registers.
// ---------------------------------------------------------------------------
template<bool IS_GEN>
__global__ __launch_bounds__(256) void k_scan(
    const float* __restrict__ xin_f32,        // inf: x_emb fp32 [LB][64]
    const u16* __restrict__ xin_b16,          // gen: gen_in bf16 [LB][128]
    const float* __restrict__ Wih,            // [192][CIN]
    const float* __restrict__ Whh,            // [192][64]
    const float* __restrict__ bih, const float* __restrict__ bhh,
    u16* __restrict__ dseq_out,               // inf
    float* __restrict__ hseq, float* __restrict__ hn)  // gen
{
  constexpr int CIN = IS_GEN ? 128 : 64;
  constexpr int KC  = CIN / 32;
  constexpr int SX  = IS_GEN ? 136 : 88;

  __shared__ u16 ht[16*88];
  __shared__ u16 xt[2][16*SX];

  const int t = threadIdx.x;
  const int lane = t & 63, wave = t >> 6;
  const int l15 = lane & 15, l4 = lane >> 4;
  const int b0 = blockIdx.x * 16;
  const int kcol = wave*16 + l15;   // this lane's gate/hidden column

  // weight fragments in registers
  bf16x8 wihf[3][KC], whhf[3][2];
  float bi[3], bh[3];
  #pragma unroll
  for (int g = 0; g < 3; ++g) {
    int grow = g*64 + kcol;
    #pragma unroll
    for (int kc = 0; kc < KC; ++kc)
      wihf[g][kc] = bfrag_f32(Wih + (size_t)grow*CIN + kc*32 + l4*8);
    #pragma unroll
    for (int kc = 0; kc < 2; ++kc)
      whhf[g][kc] = bfrag_f32(Whh + (size_t)grow*64 + kc*32 + l4*8);
    bi[g] = bih[grow];
    bh[g] = bhh[grow];
  }

  auto stage = [&](int s, u16* dst){
    int r = t >> 4, q = t & 15;
    if constexpr (!IS_GEN) {
      const float* p = xin_f32 + ((size_t)s*BATCH + b0 + r)*64 + q*4;
      float4 v = *(const float4*)p;
      bf16x4 w; w[0]=f2bs(v.x); w[1]=f2bs(v.y); w[2]=f2bs(v.z); w[3]=f2bs(v.w);
      *(bf16x4*)(dst + r*88 + q*4) = w;
    } else {
      const u16* p = xin_b16 + ((size_t)s*BATCH + b0 + r)*128 + q*8;
      *(bf16x8*)(dst + r*136 + q*8) = *(const bf16x8*)p;
    }
  };

  float h[4] = {0.f,0.f,0.f,0.f};
  stage(0, xt[0]);

  for (int step = 0; step < L_T; ++step) {
    #pragma unroll
    for (int i = 0; i < 4; ++i) {
      ht[(l4*4 + i)*88 + kcol] = (u16)f2bs(h[i]);
      if (IS_GEN)
        hseq[((size_t)step*BATCH + b0 + l4*4 + i)*64 + kcol] = h[i];  // pre-update state
    }
    __syncthreads();

    bf16x8 ha0 = *(const bf16x8*)(ht + l15*88 + l4*8);
    bf16x8 ha1 = *(const bf16x8*)(ht + l15*88 + 32 + l4*8);
    bf16x8 xa[KC];
    const u16* xb = xt[step & 1];
    #pragma unroll
    for (int kc = 0; kc < KC; ++kc)
      xa[kc] = *(const bf16x8*)(xb + l15*SX + kc*32 + l4*8);

    if (step + 1 < L_T) stage(step + 1, xt[(step + 1) & 1]);

    f32x4 gi[3], gh[3];
    #pragma unroll
    for (int g = 0; g < 3; ++g) {
      f32x4 a = {0.f,0.f,0.f,0.f};
      #pragma unroll
      for (int kc = 0; kc < KC; ++kc) a = MFMA_B16(xa[kc], wihf[g][kc], a);
      gi[g] = a;
      f32x4 b = {0.f,0.f,0.f,0.f};
      b = MFMA_B16(ha0, whhf[g][0], b);
      b = MFMA_B16(ha1, whhf[g][1], b);
      gh[g] = b;
    }

    #pragma unroll
    for (int i = 0; i < 4; ++i) {
      float r = sigmoidf_(gi[0][i] + bi[0] + gh[0][i] + bh[0]);
      float z = sigmoidf_(gi[1][i] + bi[1] + gh[1][i] + bh[1]);
      float n = tanhf_(gi[2][i] + bi[2] + r*(gh[2][i] + bh[2]));
      h[i] = (1.f - z)*n + z*h[i];
      if (!IS_GEN)
        dseq_out[((size_t)step*BATCH + b0 + l4*4 + i)*64 + kcol] = (u16)f2bs(h[i]);
    }
    __syncthreads();
  }

  if (IS_GEN) {
    #pragma unroll
    for (int i = 0; i < 4; ++i)
      hn[((size_t)b0 + l4*4 + i)*64 + kcol] = h[i];
  }
}

// ---------------------------------------------------------------------------

extern "C" void kernel_launch(void* const* d_in, const int* in_sizes, int n_in,
                              void* d_out, int out_size, void* d_ws, size_t ws_size,
                              hipStream_t stream) {
  const float* ext  = (const float*)d_in[0];
  const float* obs  = (const float*)d_in[1];
  const float* eps  = (const float*)d_in[2];
  const float* puW1 = (const float*)d_in[3];  const float* pub1 = (const float*)d_in[4];
  const float* puW2 = (const float*)d_in[5];  const float* pub2 = (const float*)d_in[6];
  const float* pxW1 = (const float*)d_in[7];  const float* pxb1 = (const float*)d_in[8];
  const float* pxW2 = (const float*)d_in[9];  const float* pxb2 = (const float*)d_in[10];
  const float* pzW1 = (const float*)d_in[11]; const float* pzb1 = (const float*)d_in[12];
  const float* pzW2 = (const float*)d_in[13]; const float* pzb2 = (const float*)d_in[14];
  const float* poW1 = (const float*)d_in[15]; const float* pob1 = (const float*)d_in[16];
  const float* poW2 = (const float*)d_in[17]; const float* pob2 = (const float*)d_in[18];
  const float* poWmu= (const float*)d_in[19]; const float* pobmu= (const float*)d_in[20];
  const float* poWls= (const float*)d_in[21]; const float* pobls= (const float*)d_in[22];
  const float* iWih = (const float*)d_in[23]; const float* iWhh = (const float*)d_in[24];
  const float* ibih = (const float*)d_in[25]; const float* ibhh = (const float*)d_in[26];
  const float* gWih = (const float*)d_in[27]; const float* gWhh = (const float*)d_in[28];
  const float* gbih = (const float*)d_in[29]; const float* gbhh = (const float*)d_in[30];

  float* out = (float*)d_out;
  const size_t OFF_MU   = 0;
  const size_t OFF_LS   = (size_t)LB*32;
  const size_t OFF_S    = (size_t)LB*64;
  const size_t OFF_HSEQ = (size_t)LB*96;
  const size_t OFF_XEMB = (size_t)LB*96 + (size_t)LB*64;
  const size_t OFF_HN   = OFF_XEMB + (size_t)LB*64;

  u16* gen_in = (u16*)d_ws;                         // [LB][128] bf16 (z cols 0..63, u cols 64..127)
  u16* dseq   = (u16*)(out + OFF_HSEQ);             // park bf16 d_seq in h_seq region (overwritten later)

  const int NT = LB/64;

  // u_emb -> gen_in cols 64..127
  k_preprocess<<<NT, 256, 0, stream>>>(ext, puW1, pub1, puW2, pub2, gen_in, 128, 64, nullptr);
  // x_emb -> fp32 output
  k_preprocess<<<NT, 256, 0, stream>>>(obs, pxW1, pxb1, pxW2, pxb2, nullptr, 0, 0, out + OFF_XEMB);
  // inference GRU scan -> d_seq (bf16)
  k_scan<false><<<64, 256, 0, stream>>>(out + OFF_XEMB, nullptr, iWih, iWhh, ibih, ibhh,
                                        dseq, nullptr, nullptr);
  // posterior + sample
  k_posterior<<<NT, 256, 0, stream>>>(dseq, eps, poW1, pob1, poW2, pob2,
                                      poWmu, pobmu, poWls, pobls,
                                      out + OFF_MU, out + OFF_LS, out + OFF_S);
  // z_emb -> gen_in cols 0..63
  k_preprocess<<<NT, 256, 0, stream>>>(out + OFF_S, pzW1, pzb1, pzW2, pzb2, gen_in, 128, 0, nullptr);
  // generative GRU scan -> h_seq, hn
  k_scan<true><<<64, 256, 0, stream>>>(nullptr, gen_in, gWih, gWhh, gbih, gbhh,
                                       nullptr, out + OFF_HSEQ, out + OFF_HN);
}

// Round 2
// 1074.617 us; speedup vs baseline: 1.3200x; 1.3200x over previous
//
#include <hip/hip_runtime.h>

#define L_T 512
#define BATCH 1024
#define LB (L_T*BATCH)

typedef short bf16x8 __attribute__((ext_vector_type(8)));
typedef short bf16x4 __attribute__((ext_vector_type(4)));
typedef float f32x4 __attribute__((ext_vector_type(4)));
typedef unsigned short u16;

#define MFMA_B16(a,b,c) __builtin_amdgcn_mfma_f32_16x16x32_bf16((a),(b),(c),0,0,0)

__device__ __forceinline__ short f2bs(float f){
  union{float f; unsigned u;} c; c.f=f;
  unsigned r = (c.u + 0x7FFFu + ((c.u>>16)&1u)) >> 16;
  return (short)r;
}

__device__ __forceinline__ float sigmoidf_(float x){ return 1.0f/(1.0f + __expf(-x)); }
// tanh via 1 - 2/(1+e^{2x}); saturates correctly at +-inf without NaN
__device__ __forceinline__ float tanhf_(float x){ return 1.0f - 2.0f/(1.0f + __expf(2.0f*x)); }

__device__ __forceinline__ void store8(u16* d, float4 a, float4 b){
  bf16x8 v;
  v[0]=f2bs(a.x); v[1]=f2bs(a.y); v[2]=f2bs(a.z); v[3]=f2bs(a.w);
  v[4]=f2bs(b.x); v[5]=f2bs(b.y); v[6]=f2bs(b.z); v[7]=f2bs(b.w);
  *(bf16x8*)d = v;
}

__device__ __forceinline__ bf16x8 bfrag_f32(const float* p){
  float4 a = *(const float4*)p;
  float4 b = *(const float4*)(p+4);
  bf16x8 v;
  v[0]=f2bs(a.x); v[1]=f2bs(a.y); v[2]=f2bs(a.z); v[3]=f2bs(a.w);
  v[4]=f2bs(b.x); v[5]=f2bs(b.y); v[6]=f2bs(b.z); v[7]=f2bs(b.w);
  return v;
}

// ---------------------------------------------------------------------------
// K1: two-layer preprocess  out = relu(relu(x@W1.T+b1)@W2.T+b2), Cin=32 fixed.
// One 64-row tile per block, 256 threads (4 waves x 16-row subtiles).
// ---------------------------------------------------------------------------
__global__ __launch_bounds__(256) void k_preprocess(
    const float* __restrict__ src,            // [LB][32]
    const float* __restrict__ W1,             // [64][32]
    const float* __restrict__ b1,             // [64]
    const float* __restrict__ W2,             // [64][64]
    const float* __restrict__ b2,             // [64]
    u16* __restrict__ out_b16, int ostride, int ooff,  // optional bf16 out
    float* __restrict__ out_f32)              // optional fp32 out [LB][64]
{
  __shared__ u16 in_t[64*40];
  __shared__ u16 w1t[64*40];
  __shared__ u16 w2t[64*88];
  __shared__ u16 t1t[64*88];
  __shared__ float lb1[64], lb2[64];

  const int t = threadIdx.x;
  const size_t row0 = (size_t)blockIdx.x * 64;

  {
    int r = t>>2, q = t&3;
    const float* ps = src + (row0 + r)*32 + q*8;
    store8(in_t + r*40 + q*8, *(const float4*)ps, *(const float4*)(ps+4));
    const float* pw = W1 + r*32 + q*8;
    store8(w1t + r*40 + q*8, *(const float4*)pw, *(const float4*)(pw+4));
    const float* pw2 = W2 + r*64 + q*16;
    store8(w2t + r*88 + q*16,     *(const float4*)pw2,     *(const float4*)(pw2+4));
    store8(w2t + r*88 + q*16 + 8, *(const float4*)(pw2+8), *(const float4*)(pw2+12));
    if (t < 64) lb1[t] = b1[t];
    else if (t < 128) lb2[t-64] = b2[t-64];
  }
  __syncthreads();

  const int lane = t & 63, wave = t >> 6;
  const int l15 = lane & 15, l4 = lane >> 4;
  const int rs = wave*16;

  // layer 1 (K=32: one k-chunk)
  {
    bf16x8 a = *(const bf16x8*)(in_t + (rs + l15)*40 + l4*8);
    #pragma unroll
    for (int ct = 0; ct < 4; ++ct) {
      f32x4 acc = {0.f,0.f,0.f,0.f};
      bf16x8 bw = *(const bf16x8*)(w1t + (ct*16 + l15)*40 + l4*8);
      acc = MFMA_B16(a, bw, acc);
      float bias = lb1[ct*16 + l15];
      #pragma unroll
      for (int i = 0; i < 4; ++i) {
        float v = fmaxf(acc[i] + bias, 0.f);
        t1t[(rs + l4*4 + i)*88 + ct*16 + l15] = (u16)f2bs(v);
      }
    }
  }
  __syncthreads();

  // layer 2 (K=64: two k-chunks)
  {
    bf16x8 a0 = *(const bf16x8*)(t1t + (rs + l15)*88 + l4*8);
    bf16x8 a1 = *(const bf16x8*)(t1t + (rs + l15)*88 + 32 + l4*8);
    #pragma unroll
    for (int ct = 0; ct < 4; ++ct) {
      f32x4 acc = {0.f,0.f,0.f,0.f};
      bf16x8 b0 = *(const bf16x8*)(w2t + (ct*16 + l15)*88 + l4*8);
      bf16x8 b1v = *(const bf16x8*)(w2t + (ct*16 + l15)*88 + 32 + l4*8);
      acc = MFMA_B16(a0, b0, acc);
      acc = MFMA_B16(a1, b1v, acc);
      float bias = lb2[ct*16 + l15];
      #pragma unroll
      for (int i = 0; i < 4; ++i) {
        float v = fmaxf(acc[i] + bias, 0.f);
        size_t gr = row0 + rs + l4*4 + i;
        int col = ct*16 + l15;
        if (out_b16) out_b16[gr*(size_t)ostride + ooff + col] = (u16)f2bs(v);
        if (out_f32) out_f32[gr*64 + col] = v;
      }
    }
  }
}

// ---------------------------------------------------------------------------
// K2: posterior DBlock + reparam sample.
// ---------------------------------------------------------------------------
__global__ __launch_bounds__(256) void k_posterior(
    const u16* __restrict__ dseq,             // [LB][64] bf16
    const float* __restrict__ eps,            // [LB][32]
    const float* __restrict__ W1, const float* __restrict__ b1,
    const float* __restrict__ W2, const float* __restrict__ b2,
    const float* __restrict__ Wmu, const float* __restrict__ bmu,
    const float* __restrict__ Wls, const float* __restrict__ bls,
    float* __restrict__ out_mu, float* __restrict__ out_ls, float* __restrict__ out_s)
{
  __shared__ u16 dt[64*88], w1t[64*88], w2t[64*88], tt[64*88];
  __shared__ u16 wmut[32*88], wlst[32*88];
  __shared__ float lb1[64], lb2[64], lbmu[32], lbls[32];

  const int t = threadIdx.x;
  const size_t row0 = (size_t)blockIdx.x * 64;

  {
    int r = t>>2, q = t&3;
    const u16* pd = dseq + (row0 + r)*64 + q*16;
    *(bf16x8*)(dt + r*88 + q*16)     = *(const bf16x8*)pd;
    *(bf16x8*)(dt + r*88 + q*16 + 8) = *(const bf16x8*)(pd + 8);
    const float* p1 = W1 + r*64 + q*16;
    store8(w1t + r*88 + q*16,     *(const float4*)p1,     *(const float4*)(p1+4));
    store8(w1t + r*88 + q*16 + 8, *(const float4*)(p1+8), *(const float4*)(p1+12));
    const float* p2 = W2 + r*64 + q*16;
    store8(w2t + r*88 + q*16,     *(const float4*)p2,     *(const float4*)(p2+4));
    store8(w2t + r*88 + q*16 + 8, *(const float4*)(p2+8), *(const float4*)(p2+12));
    if (t < 128) {
      int r2 = t>>2, q2 = t&3;   // r2 in 0..31
      const float* pm = Wmu + r2*64 + q2*16;
      store8(wmut + r2*88 + q2*16,     *(const float4*)pm,     *(const float4*)(pm+4));
      store8(wmut + r2*88 + q2*16 + 8, *(const float4*)(pm+8), *(const float4*)(pm+12));
    } else {
      int t2 = t - 128; int r2 = t2>>2, q2 = t2&3;
      const float* pl = Wls + r2*64 + q2*16;
      store8(wlst + r2*88 + q2*16,     *(const float4*)pl,     *(const float4*)(pl+4));
      store8(wlst + r2*88 + q2*16 + 8, *(const float4*)(pl+8), *(const float4*)(pl+12));
    }
    if (t < 64) lb1[t] = b1[t];
    else if (t < 128) lb2[t-64] = b2[t-64];
    else if (t < 160) lbmu[t-128] = bmu[t-128];
    else if (t < 192) lbls[t-160] = bls[t-160];
  }
  __syncthreads();

  const int lane = t & 63, wave = t >> 6;
  const int l15 = lane & 15, l4 = lane >> 4;
  const int rs = wave*16;

  // gated hidden
  {
    bf16x8 a0 = *(const bf16x8*)(dt + (rs + l15)*88 + l4*8);
    bf16x8 a1 = *(const bf16x8*)(dt + (rs + l15)*88 + 32 + l4*8);
    #pragma unroll
    for (int ct = 0; ct < 4; ++ct) {
      f32x4 c1 = {0.f,0.f,0.f,0.f}, c2 = {0.f,0.f,0.f,0.f};
      bf16x8 w1a = *(const bf16x8*)(w1t + (ct*16 + l15)*88 + l4*8);
      bf16x8 w1b = *(const bf16x8*)(w1t + (ct*16 + l15)*88 + 32 + l4*8);
      bf16x8 w2a = *(const bf16x8*)(w2t + (ct*16 + l15)*88 + l4*8);
      bf16x8 w2b = *(const bf16x8*)(w2t + (ct*16 + l15)*88 + 32 + l4*8);
      c1 = MFMA_B16(a0, w1a, c1); c1 = MFMA_B16(a1, w1b, c1);
      c2 = MFMA_B16(a0, w2a, c2); c2 = MFMA_B16(a1, w2b, c2);
      float bb1 = lb1[ct*16 + l15], bb2 = lb2[ct*16 + l15];
      #pragma unroll
      for (int i = 0; i < 4; ++i) {
        float tv = fmaxf(c1[i] + bb1, 0.f) * sigmoidf_(c2[i] + bb2);
        tt[(rs + l4*4 + i)*88 + ct*16 + l15] = (u16)f2bs(tv);
      }
    }
  }
  __syncthreads();

  // heads + sample
  {
    bf16x8 a0 = *(const bf16x8*)(tt + (rs + l15)*88 + l4*8);
    bf16x8 a1 = *(const bf16x8*)(tt + (rs + l15)*88 + 32 + l4*8);
    #pragma unroll
    for (int ct = 0; ct < 2; ++ct) {
      f32x4 cmu = {0.f,0.f,0.f,0.f}, cls = {0.f,0.f,0.f,0.f};
      bf16x8 wma = *(const bf16x8*)(wmut + (ct*16 + l15)*88 + l4*8);
      bf16x8 wmb = *(const bf16x8*)(wmut + (ct*16 + l15)*88 + 32 + l4*8);
      bf16x8 wla = *(const bf16x8*)(wlst + (ct*16 + l15)*88 + l4*8);
      bf16x8 wlb = *(const bf16x8*)(wlst + (ct*16 + l15)*88 + 32 + l4*8);
      cmu = MFMA_B16(a0, wma, cmu); cmu = MFMA_B16(a1, wmb, cmu);
      cls = MFMA_B16(a0, wla, cls); cls = MFMA_B16(a1, wlb, cls);
      float bm = lbmu[ct*16 + l15], bl = lbls[ct*16 + l15];
      #pragma unroll
      for (int i = 0; i < 4; ++i) {
        size_t R = row0 + rs + l4*4 + i;
        int col = ct*16 + l15;
        float mu = cmu[i] + bm;
        float ls = cls[i] + bl;
        float e  = eps[R*32 + col];
        float s  = mu + __expf(0.5f*ls)*e;
        out_mu[R*32 + col] = mu;
        out_ls[R*32 + col] = ls;
        out_s [R*32 + col] = s;
      }
    }
  }
}

// ---------------------------------------------------------------------------
// K3/K4: GRU scan, barrier-cheap version.
//  - x A-fragments loaded straight from global into registers (no LDS),
//    software-pipelined 2 steps ahead; vmcnt is NEVER drained by a barrier.
//  - raw s_barrier with explicit lgkmcnt(0) only on the h write->read edge.
//  - biases folded into MFMA C-operand init.
// 64 blocks x 256 threads; each block owns 16 batch rows; wave w owns gate
// column slice w*16..w*16+15 of each of the 3 gates.
// ---------------------------------------------------------------------------
template<bool IS_GEN>
__global__ __launch_bounds__(256, 1) void k_scan(
    const u16* __restrict__ xin,              // [LB][CIN] bf16
    const float* __restrict__ Wih,            // [192][CIN]
    const float* __restrict__ Whh,            // [192][64]
    const float* __restrict__ bih, const float* __restrict__ bhh,
    u16* __restrict__ dseq_out,               // inf: bf16 [LB][64]
    float* __restrict__ hseq, float* __restrict__ hn)  // gen
{
  constexpr int CIN = IS_GEN ? 128 : 64;
  constexpr int KC  = CIN / 32;
  constexpr int SH  = 72;                     // u16 stride of h tile

  __shared__ u16 ht[16*SH];

  const int t = threadIdx.x;
  const int lane = t & 63, wave = t >> 6;
  const int l15 = lane & 15, l4 = lane >> 4;
  const int b0 = blockIdx.x * 16;
  const int kcol = wave*16 + l15;             // this lane's gate/hidden column

  // weight fragments in registers; biases pre-combined
  bf16x8 wihf[3][KC], whhf[3][2];
  #pragma unroll
  for (int g = 0; g < 3; ++g) {
    int grow = g*64 + kcol;
    #pragma unroll
    for (int kc = 0; kc < KC; ++kc)
      wihf[g][kc] = bfrag_f32(Wih + (size_t)grow*CIN + kc*32 + l4*8);
    #pragma unroll
    for (int kc = 0; kc < 2; ++kc)
      whhf[g][kc] = bfrag_f32(Whh + (size_t)grow*64 + kc*32 + l4*8);
  }
  const float brz0 = bih[kcol]       + bhh[kcol];        // r-gate bias sum
  const float brz1 = bih[64 + kcol]  + bhh[64 + kcol];   // z-gate bias sum
  const float bin  = bih[128 + kcol];                    // n-gate input bias
  const float bhn  = bhh[128 + kcol];                    // n-gate hidden bias

  // per-lane global base for x A-fragments: row (b0+l15), cols l4*8 + kc*32
  const u16* xbase = xin + ((size_t)b0 + l15)*CIN + l4*8;
  const size_t xstep = (size_t)BATCH*CIN;

  // software pipeline: xA holds even step, xB odd step
  bf16x8 xA[KC], xB[KC];
  #pragma unroll
  for (int kc = 0; kc < KC; ++kc) {
    xA[kc] = *(const bf16x8*)(xbase + kc*32);
    xB[kc] = *(const bf16x8*)(xbase + xstep + kc*32);
  }

  float h[4] = {0.f,0.f,0.f,0.f};

  auto body = [&](bf16x8 (&X)[KC], int s) {
    // publish h (bf16) to LDS; optional global h emission
    #pragma unroll
    for (int i = 0; i < 4; ++i) {
      ht[(l4*4 + i)*SH + kcol] = (u16)f2bs(h[i]);
      if (IS_GEN)
        hseq[((size_t)s*BATCH + b0 + l4*4 + i)*64 + kcol] = h[i];  // pre-update state
    }
    // write->read edge: only LDS ops need to drain; vmcnt stays in flight
    asm volatile("s_waitcnt lgkmcnt(0)\n\ts_barrier" ::: "memory");

    bf16x8 ha0 = *(const bf16x8*)(ht + l15*SH + l4*8);
    bf16x8 ha1 = *(const bf16x8*)(ht + l15*SH + 32 + l4*8);

    f32x4 gi0 = {0.f,0.f,0.f,0.f}, gi1 = {0.f,0.f,0.f,0.f};
    f32x4 gi2 = {bin,bin,bin,bin};
    #pragma unroll
    for (int kc = 0; kc < KC; ++kc) {
      gi0 = MFMA_B16(X[kc], wihf[0][kc], gi0);
      gi1 = MFMA_B16(X[kc], wihf[1][kc], gi1);
      gi2 = MFMA_B16(X[kc], wihf[2][kc], gi2);
    }
    f32x4 gh0 = {brz0,brz0,brz0,brz0};
    f32x4 gh1 = {brz1,brz1,brz1,brz1};
    f32x4 gh2 = {bhn,bhn,bhn,bhn};
    gh0 = MFMA_B16(ha0, whhf[0][0], gh0); gh0 = MFMA_B16(ha1, whhf[0][1], gh0);
    gh1 = MFMA_B16(ha0, whhf[1][0], gh1); gh1 = MFMA_B16(ha1, whhf[1][1], gh1);
    gh2 = MFMA_B16(ha0, whhf[2][0], gh2); gh2 = MFMA_B16(ha1, whhf[2][1], gh2);

    // refill X for step s+2 (stays in flight across the raw barriers)
    {
      size_t snx = (size_t)((s + 2 < L_T) ? s + 2 : L_T - 1);
      const u16* p = xbase + snx*xstep;
      #pragma unroll
      for (int kc = 0; kc < KC; ++kc)
        X[kc] = *(const bf16x8*)(p + kc*32);
    }

    #pragma unroll
    for (int i = 0; i < 4; ++i) {
      float r = sigmoidf_(gi0[i] + gh0[i]);
      float z = sigmoidf_(gi1[i] + gh1[i]);
      float n = tanhf_(gi2[i] + r*gh2[i]);
      h[i] = z*(h[i] - n) + n;
      if (!IS_GEN)
        dseq_out[((size_t)s*BATCH + b0 + l4*4 + i)*64 + kcol] = (u16)f2bs(h[i]);
    }
    // WAR edge before next step's ht write; reads already retired locally
    asm volatile("s_barrier" ::: "memory");
  };

  for (int step = 0; step < L_T; step += 2) {
    body(xA, step);
    body(xB, step + 1);
  }

  if (IS_GEN) {
    #pragma unroll
    for (int i = 0; i < 4; ++i)
      hn[((size_t)b0 + l4*4 + i)*64 + kcol] = h[i];
  }
}

// ---------------------------------------------------------------------------

extern "C" void kernel_launch(void* const* d_in, const int* in_sizes, int n_in,
                              void* d_out, int out_size, void* d_ws, size_t ws_size,
                              hipStream_t stream) {
  const float* ext  = (const float*)d_in[0];
  const float* obs  = (const float*)d_in[1];
  const float* eps  = (const float*)d_in[2];
  const float* puW1 = (const float*)d_in[3];  const float* pub1 = (const float*)d_in[4];
  const float* puW2 = (const float*)d_in[5];  const float* pub2 = (const float*)d_in[6];
  const float* pxW1 = (const float*)d_in[7];  const float* pxb1 = (const float*)d_in[8];
  const float* pxW2 = (const float*)d_in[9];  const float* pxb2 = (const float*)d_in[10];
  const float* pzW1 = (const float*)d_in[11]; const float* pzb1 = (const float*)d_in[12];
  const float* pzW2 = (const float*)d_in[13]; const float* pzb2 = (const float*)d_in[14];
  const float* poW1 = (const float*)d_in[15]; const float* pob1 = (const float*)d_in[16];
  const float* poW2 = (const float*)d_in[17]; const float* pob2 = (const float*)d_in[18];
  const float* poWmu= (const float*)d_in[19]; const float* pobmu= (const float*)d_in[20];
  const float* poWls= (const float*)d_in[21]; const float* pobls= (const float*)d_in[22];
  const float* iWih = (const float*)d_in[23]; const float* iWhh = (const float*)d_in[24];
  const float* ibih = (const float*)d_in[25]; const float* ibhh = (const float*)d_in[26];
  const float* gWih = (const float*)d_in[27]; const float* gWhh = (const float*)d_in[28];
  const float* gbih = (const float*)d_in[29]; const float* gbhh = (const float*)d_in[30];

  float* out = (float*)d_out;
  const size_t OFF_MU   = 0;
  const size_t OFF_LS   = (size_t)LB*32;
  const size_t OFF_S    = (size_t)LB*64;
  const size_t OFF_HSEQ = (size_t)LB*96;
  const size_t OFF_XEMB = (size_t)LB*96 + (size_t)LB*64;
  const size_t OFF_HN   = OFF_XEMB + (size_t)LB*64;

  u16* gen_in = (u16*)d_ws;                          // [LB][128] bf16 (z | u)
  u16* dseq   = (u16*)(out + OFF_HSEQ);              // bf16 park, 1st half of hseq region
  u16* xemb16 = (u16*)(out + OFF_HSEQ + (size_t)LB*32);  // bf16 park, 2nd half

  const int NT = LB/64;

  // u_emb -> gen_in cols 64..127
  k_preprocess<<<NT, 256, 0, stream>>>(ext, puW1, pub1, puW2, pub2, gen_in, 128, 64, nullptr);
  // x_emb -> fp32 output + bf16 park for the inf scan
  k_preprocess<<<NT, 256, 0, stream>>>(obs, pxW1, pxb1, pxW2, pxb2, xemb16, 64, 0, out + OFF_XEMB);
  // inference GRU scan -> d_seq (bf16 park)
  k_scan<false><<<64, 256, 0, stream>>>(xemb16, iWih, iWhh, ibih, ibhh,
                                        dseq, nullptr, nullptr);
  // posterior + sample
  k_posterior<<<NT, 256, 0, stream>>>(dseq, eps, poW1, pob1, poW2, pob2,
                                      poWmu, pobmu, poWls, pobls,
                                      out + OFF_MU, out + OFF_LS, out + OFF_S);
  // z_emb -> gen_in cols 0..63
  k_preprocess<<<NT, 256, 0, stream>>>(out + OFF_S, pzW1, pzb1, pzW2, pzb2, gen_in, 128, 0, nullptr);
  // generative GRU scan -> h_seq, hn
  k_scan<true><<<64, 256, 0, stream>>>(gen_in, gWih, gWhh, gbih, gbhh,
                                       nullptr, out + OFF_HSEQ, out + OFF_HN);
}

// Round 3
// 1044.406 us; speedup vs baseline: 1.3582x; 1.0289x over previous
//
#include <hip/hip_runtime.h>

#define L_T 512
#define BATCH 1024
#define LB (L_T*BATCH)

typedef short bf16x8 __attribute__((ext_vector_type(8)));
typedef short bf16x4 __attribute__((ext_vector_type(4)));
typedef float f32x4 __attribute__((ext_vector_type(4)));
typedef unsigned short u16;

#define MFMA_B16(a,b,c) __builtin_amdgcn_mfma_f32_16x16x32_bf16((a),(b),(c),0,0,0)

__device__ __forceinline__ short f2bs(float f){
  union{float f; unsigned u;} c; c.f=f;
  unsigned r = (c.u + 0x7FFFu + ((c.u>>16)&1u)) >> 16;
  return (short)r;
}

__device__ __forceinline__ float sigmoidf_(float x){ return 1.0f/(1.0f + __expf(-x)); }
__device__ __forceinline__ float tanhf_(float x){ return 1.0f - 2.0f/(1.0f + __expf(2.0f*x)); }

__device__ __forceinline__ void store8(u16* d, float4 a, float4 b){
  bf16x8 v;
  v[0]=f2bs(a.x); v[1]=f2bs(a.y); v[2]=f2bs(a.z); v[3]=f2bs(a.w);
  v[4]=f2bs(b.x); v[5]=f2bs(b.y); v[6]=f2bs(b.z); v[7]=f2bs(b.w);
  *(bf16x8*)d = v;
}

__device__ __forceinline__ bf16x8 bfrag_f32(const float* p){
  float4 a = *(const float4*)p;
  float4 b = *(const float4*)(p+4);
  bf16x8 v;
  v[0]=f2bs(a.x); v[1]=f2bs(a.y); v[2]=f2bs(a.z); v[3]=f2bs(a.w);
  v[4]=f2bs(b.x); v[5]=f2bs(b.y); v[6]=f2bs(b.z); v[7]=f2bs(b.w);
  return v;
}

__device__ __forceinline__ void dma16(const void* g, void* l){
  __builtin_amdgcn_global_load_lds(
      (const __attribute__((address_space(1))) void*)g,
      (__attribute__((address_space(3))) void*)l, 16, 0, 0);
}

// ---------------------------------------------------------------------------
// K1: two-layer preprocess  out = relu(relu(x@W1.T+b1)@W2.T+b2), Cin=32 fixed.
// ---------------------------------------------------------------------------
__global__ __launch_bounds__(256) void k_preprocess(
    const float* __restrict__ src,            // [LB][32]
    const float* __restrict__ W1,             // [64][32]
    const float* __restrict__ b1,             // [64]
    const float* __restrict__ W2,             // [64][64]
    const float* __restrict__ b2,             // [64]
    u16* __restrict__ out_b16, int ostride, int ooff,  // optional bf16 out
    float* __restrict__ out_f32)              // optional fp32 out [LB][64]
{
  __shared__ u16 in_t[64*40];
  __shared__ u16 w1t[64*40];
  __shared__ u16 w2t[64*88];
  __shared__ u16 t1t[64*88];
  __shared__ float lb1[64], lb2[64];

  const int t = threadIdx.x;
  const size_t row0 = (size_t)blockIdx.x * 64;

  {
    int r = t>>2, q = t&3;
    const float* ps = src + (row0 + r)*32 + q*8;
    store8(in_t + r*40 + q*8, *(const float4*)ps, *(const float4*)(ps+4));
    const float* pw = W1 + r*32 + q*8;
    store8(w1t + r*40 + q*8, *(const float4*)pw, *(const float4*)(pw+4));
    const float* pw2 = W2 + r*64 + q*16;
    store8(w2t + r*88 + q*16,     *(const float4*)pw2,     *(const float4*)(pw2+4));
    store8(w2t + r*88 + q*16 + 8, *(const float4*)(pw2+8), *(const float4*)(pw2+12));
    if (t < 64) lb1[t] = b1[t];
    else if (t < 128) lb2[t-64] = b2[t-64];
  }
  __syncthreads();

  const int lane = t & 63, wave = t >> 6;
  const int l15 = lane & 15, l4 = lane >> 4;
  const int rs = wave*16;

  // layer 1 (K=32)
  {
    bf16x8 a = *(const bf16x8*)(in_t + (rs + l15)*40 + l4*8);
    #pragma unroll
    for (int ct = 0; ct < 4; ++ct) {
      f32x4 acc = {0.f,0.f,0.f,0.f};
      bf16x8 bw = *(const bf16x8*)(w1t + (ct*16 + l15)*40 + l4*8);
      acc = MFMA_B16(a, bw, acc);
      float bias = lb1[ct*16 + l15];
      #pragma unroll
      for (int i = 0; i < 4; ++i) {
        float v = fmaxf(acc[i] + bias, 0.f);
        t1t[(rs + l4*4 + i)*88 + ct*16 + l15] = (u16)f2bs(v);
      }
    }
  }
  __syncthreads();

  // layer 2 (K=64)
  {
    bf16x8 a0 = *(const bf16x8*)(t1t + (rs + l15)*88 + l4*8);
    bf16x8 a1 = *(const bf16x8*)(t1t + (rs + l15)*88 + 32 + l4*8);
    #pragma unroll
    for (int ct = 0; ct < 4; ++ct) {
      f32x4 acc = {0.f,0.f,0.f,0.f};
      bf16x8 b0 = *(const bf16x8*)(w2t + (ct*16 + l15)*88 + l4*8);
      bf16x8 b1v = *(const bf16x8*)(w2t + (ct*16 + l15)*88 + 32 + l4*8);
      acc = MFMA_B16(a0, b0, acc);
      acc = MFMA_B16(a1, b1v, acc);
      float bias = lb2[ct*16 + l15];
      #pragma unroll
      for (int i = 0; i < 4; ++i) {
        float v = fmaxf(acc[i] + bias, 0.f);
        size_t gr = row0 + rs + l4*4 + i;
        int col = ct*16 + l15;
        if (out_b16) out_b16[gr*(size_t)ostride + ooff + col] = (u16)f2bs(v);
        if (out_f32) out_f32[gr*64 + col] = v;
      }
    }
  }
}

// ---------------------------------------------------------------------------
// K2: posterior DBlock + reparam sample.
// ---------------------------------------------------------------------------
__global__ __launch_bounds__(256) void k_posterior(
    const u16* __restrict__ dseq,             // [LB][64] bf16
    const float* __restrict__ eps,            // [LB][32]
    const float* __restrict__ W1, const float* __restrict__ b1,
    const float* __restrict__ W2, const float* __restrict__ b2,
    const float* __restrict__ Wmu, const float* __restrict__ bmu,
    const float* __restrict__ Wls, const float* __restrict__ bls,
    float* __restrict__ out_mu, float* __restrict__ out_ls, float* __restrict__ out_s)
{
  __shared__ u16 dt[64*88], w1t[64*88], w2t[64*88], tt[64*88];
  __shared__ u16 wmut[32*88], wlst[32*88];
  __shared__ float lb1[64], lb2[64], lbmu[32], lbls[32];

  const int t = threadIdx.x;
  const size_t row0 = (size_t)blockIdx.x * 64;

  {
    int r = t>>2, q = t&3;
    const u16* pd = dseq + (row0 + r)*64 + q*16;
    *(bf16x8*)(dt + r*88 + q*16)     = *(const bf16x8*)pd;
    *(bf16x8*)(dt + r*88 + q*16 + 8) = *(const bf16x8*)(pd + 8);
    const float* p1 = W1 + r*64 + q*16;
    store8(w1t + r*88 + q*16,     *(const float4*)p1,     *(const float4*)(p1+4));
    store8(w1t + r*88 + q*16 + 8, *(const float4*)(p1+8), *(const float4*)(p1+12));
    const float* p2 = W2 + r*64 + q*16;
    store8(w2t + r*88 + q*16,     *(const float4*)p2,     *(const float4*)(p2+4));
    store8(w2t + r*88 + q*16 + 8, *(const float4*)(p2+8), *(const float4*)(p2+12));
    if (t < 128) {
      int r2 = t>>2, q2 = t&3;
      const float* pm = Wmu + r2*64 + q2*16;
      store8(wmut + r2*88 + q2*16,     *(const float4*)pm,     *(const float4*)(pm+4));
      store8(wmut + r2*88 + q2*16 + 8, *(const float4*)(pm+8), *(const float4*)(pm+12));
    } else {
      int t2 = t - 128; int r2 = t2>>2, q2 = t2&3;
      const float* pl = Wls + r2*64 + q2*16;
      store8(wlst + r2*88 + q2*16,     *(const float4*)pl,     *(const float4*)(pl+4));
      store8(wlst + r2*88 + q2*16 + 8, *(const float4*)(pl+8), *(const float4*)(pl+12));
    }
    if (t < 64) lb1[t] = b1[t];
    else if (t < 128) lb2[t-64] = b2[t-64];
    else if (t < 160) lbmu[t-128] = bmu[t-128];
    else if (t < 192) lbls[t-160] = bls[t-160];
  }
  __syncthreads();

  const int lane = t & 63, wave = t >> 6;
  const int l15 = lane & 15, l4 = lane >> 4;
  const int rs = wave*16;

  {
    bf16x8 a0 = *(const bf16x8*)(dt + (rs + l15)*88 + l4*8);
    bf16x8 a1 = *(const bf16x8*)(dt + (rs + l15)*88 + 32 + l4*8);
    #pragma unroll
    for (int ct = 0; ct < 4; ++ct) {
      f32x4 c1 = {0.f,0.f,0.f,0.f}, c2 = {0.f,0.f,0.f,0.f};
      bf16x8 w1a = *(const bf16x8*)(w1t + (ct*16 + l15)*88 + l4*8);
      bf16x8 w1b = *(const bf16x8*)(w1t + (ct*16 + l15)*88 + 32 + l4*8);
      bf16x8 w2a = *(const bf16x8*)(w2t + (ct*16 + l15)*88 + l4*8);
      bf16x8 w2b = *(const bf16x8*)(w2t + (ct*16 + l15)*88 + 32 + l4*8);
      c1 = MFMA_B16(a0, w1a, c1); c1 = MFMA_B16(a1, w1b, c1);
      c2 = MFMA_B16(a0, w2a, c2); c2 = MFMA_B16(a1, w2b, c2);
      float bb1 = lb1[ct*16 + l15], bb2 = lb2[ct*16 + l15];
      #pragma unroll
      for (int i = 0; i < 4; ++i) {
        float tv = fmaxf(c1[i] + bb1, 0.f) * sigmoidf_(c2[i] + bb2);
        tt[(rs + l4*4 + i)*88 + ct*16 + l15] = (u16)f2bs(tv);
      }
    }
  }
  __syncthreads();

  {
    bf16x8 a0 = *(const bf16x8*)(tt + (rs + l15)*88 + l4*8);
    bf16x8 a1 = *(const bf16x8*)(tt + (rs + l15)*88 + 32 + l4*8);
    #pragma unroll
    for (int ct = 0; ct < 2; ++ct) {
      f32x4 cmu = {0.f,0.f,0.f,0.f}, cls = {0.f,0.f,0.f,0.f};
      bf16x8 wma = *(const bf16x8*)(wmut + (ct*16 + l15)*88 + l4*8);
      bf16x8 wmb = *(const bf16x8*)(wmut + (ct*16 + l15)*88 + 32 + l4*8);
      bf16x8 wla = *(const bf16x8*)(wlst + (ct*16 + l15)*88 + l4*8);
      bf16x8 wlb = *(const bf16x8*)(wlst + (ct*16 + l15)*88 + 32 + l4*8);
      cmu = MFMA_B16(a0, wma, cmu); cmu = MFMA_B16(a1, wmb, cmu);
      cls = MFMA_B16(a0, wla, cls); cls = MFMA_B16(a1, wlb, cls);
      float bm = lbmu[ct*16 + l15], bl = lbls[ct*16 + l15];
      #pragma unroll
      for (int i = 0; i < 4; ++i) {
        size_t R = row0 + rs + l4*4 + i;
        int col = ct*16 + l15;
        float mu = cmu[i] + bm;
        float ls = cls[i] + bl;
        float e  = eps[R*32 + col];
        float s  = mu + __expf(0.5f*ls)*e;
        out_mu[R*32 + col] = mu;
        out_ls[R*32 + col] = ls;
        out_s [R*32 + col] = s;
      }
    }
  }
}

// ---------------------------------------------------------------------------
// K3/K4: GRU scan v3.
//  - x staged via global_load_lds DMA in 8-step chunks (dbuf), source-swizzled
//    so ds_read_b128 x-frag reads are bank-conflict-free. ONE counted
//    s_waitcnt vmcnt(16) per chunk; no register global loads in the loop.
//  - gi MFMAs (x @ Wih^T, bias in C-init) issued BEFORE the barrier (shadowed
//    by the h publish/exchange); post-barrier path = 2-deep gh MFMA + gates.
//  - ht double-buffered -> single barrier per step.
// 64 blocks x 256 threads; block owns 16 batch rows; wave w owns gate column
// slice w*16..w*16+15 of each of the 3 gates.
// ---------------------------------------------------------------------------
template<bool IS_GEN>
__global__ __launch_bounds__(256, 1) void k_scan(
    const u16* __restrict__ xin,              // [LB][CIN] bf16
    const float* __restrict__ Wih,            // [192][CIN]
    const float* __restrict__ Whh,            // [192][64]
    const float* __restrict__ bih, const float* __restrict__ bhh,
    u16* __restrict__ dseq_out,               // inf: bf16 [LB][64]
    float* __restrict__ hseq, float* __restrict__ hn)  // gen
{
  constexpr int CIN  = IS_GEN ? 128 : 64;
  constexpr int KC   = CIN / 32;
  constexpr int SPR  = CIN*2/16;              // 16B slots per row (8 / 16)
  constexpr int SLICE_U16 = 16*CIN;           // one step-slice (1024 / 2048)
  constexpr int CHUNK_U16 = 8*SLICE_U16;      // 8 steps (8192 / 16384)
  constexpr int NCHUNK = L_T/8;               // 64
  constexpr int ISSUES_W = (CHUNK_U16*2)/(1024*4);  // per-wave DMA issues (4 / 8)
  constexpr int HT_U16 = 16*72;

  __shared__ u16 xchunk[2*CHUNK_U16];
  __shared__ u16 ht[2*HT_U16];

  const int t = threadIdx.x;
  const int lane = t & 63, wave = t >> 6;
  const int l15 = lane & 15, l4 = lane >> 4;
  const int b0 = blockIdx.x * 16;
  const int kcol = wave*16 + l15;             // this lane's gate/hidden column

  // weight fragments in registers
  bf16x8 wihf[3][KC], whhf[3][2];
  #pragma unroll
  for (int g = 0; g < 3; ++g) {
    int grow = g*64 + kcol;
    #pragma unroll
    for (int kc = 0; kc < KC; ++kc)
      wihf[g][kc] = bfrag_f32(Wih + (size_t)grow*CIN + kc*32 + l4*8);
    #pragma unroll
    for (int kc = 0; kc < 2; ++kc)
      whhf[g][kc] = bfrag_f32(Whh + (size_t)grow*64 + kc*32 + l4*8);
  }
  const float brz0 = bih[kcol]       + bhh[kcol];
  const float brz1 = bih[64 + kcol]  + bhh[64 + kcol];
  const float bin  = bih[128 + kcol];
  const float bhn  = bhh[128 + kcol];

  // DMA one 8-step chunk into xchunk[bufi]; global source pre-swizzled
  // (q ^= r&7 on 16B slots) so the b128 x-frag reads are conflict-free.
  auto issue_chunk = [&](int chunk, int bufi){
    const size_t step0 = (size_t)chunk*8;
    u16* dst0 = xchunk + bufi*CHUNK_U16;
    #pragma unroll
    for (int j = 0; j < ISSUES_W; ++j) {
      int o = (j*4 + wave)*1024;              // byte offset within chunk
      int slot = o/16 + lane;                 // this lane's 16B slot
      int r_all = slot / SPR;
      int q = slot % SPR;
      int slice = r_all >> 4, r = r_all & 15;
      int qs = q ^ (r & 7);
      const u16* g = xin + ((step0 + slice)*BATCH + b0 + r)*CIN + qs*8;
      dma16(g, dst0 + o/2);
    }
  };

  float h[4] = {0.f,0.f,0.f,0.f};
  issue_chunk(0, 0);

  for (int step = 0; step < L_T; ++step) {
    const int sp = step & 7;
    const int cb = (step >> 3) & 1;
    if (sp == 0) {
      int chunk = step >> 3;
      if (chunk + 1 < NCHUNK) issue_chunk(chunk + 1, cb ^ 1);
      if (chunk == 0) asm volatile("s_waitcnt vmcnt(0)" ::: "memory");
      else            asm volatile("s_waitcnt vmcnt(16)" ::: "memory");
    }

    // x fragments for this step (swizzled LDS read)
    const u16* xb = xchunk + cb*CHUNK_U16 + sp*SLICE_U16 + l15*CIN;
    bf16x8 xa[KC];
    #pragma unroll
    for (int kc = 0; kc < KC; ++kc)
      xa[kc] = *(const bf16x8*)(xb + (((l4 + 4*kc) ^ (l15 & 7)) * 8));

    // gi chains (pre-barrier, shadowed by publish/exchange)
    f32x4 g0 = {brz0,brz0,brz0,brz0};
    f32x4 g1 = {brz1,brz1,brz1,brz1};
    f32x4 g2 = {bin,bin,bin,bin};
    #pragma unroll
    for (int kc = 0; kc < KC; ++kc) {
      g0 = MFMA_B16(xa[kc], wihf[0][kc], g0);
      g1 = MFMA_B16(xa[kc], wihf[1][kc], g1);
      g2 = MFMA_B16(xa[kc], wihf[2][kc], g2);
    }

    // publish h (bf16) to this step's ht buffer; gen also emits pre-update h
    u16* htw = ht + (step & 1)*HT_U16;
    #pragma unroll
    for (int i = 0; i < 4; ++i) {
      htw[(l4*4 + i)*72 + kcol] = (u16)f2bs(h[i]);
      if (IS_GEN)
        hseq[((size_t)step*BATCH + b0 + l4*4 + i)*64 + kcol] = h[i];
    }

    __builtin_amdgcn_sched_barrier(0);
    asm volatile("s_waitcnt lgkmcnt(0)\n\ts_barrier" ::: "memory");

    const u16* htr = ht + (step & 1)*HT_U16;
    bf16x8 ha0 = *(const bf16x8*)(htr + l15*72 + l4*8);
    bf16x8 ha1 = *(const bf16x8*)(htr + l15*72 + 32 + l4*8);

    f32x4 gh2 = {bhn,bhn,bhn,bhn};
    g0  = MFMA_B16(ha0, whhf[0][0], g0);  g0  = MFMA_B16(ha1, whhf[0][1], g0);
    g1  = MFMA_B16(ha0, whhf[1][0], g1);  g1  = MFMA_B16(ha1, whhf[1][1], g1);
    gh2 = MFMA_B16(ha0, whhf[2][0], gh2); gh2 = MFMA_B16(ha1, whhf[2][1], gh2);

    #pragma unroll
    for (int i = 0; i < 4; ++i) {
      float r = sigmoidf_(g0[i]);
      float z = sigmoidf_(g1[i]);
      float n = tanhf_(g2[i] + r*gh2[i]);
      h[i] = z*(h[i] - n) + n;
      if (!IS_GEN)
        dseq_out[((size_t)step*BATCH + b0 + l4*4 + i)*64 + kcol] = (u16)f2bs(h[i]);
    }
  }

  if (IS_GEN) {
    #pragma unroll
    for (int i = 0; i < 4; ++i)
      hn[((size_t)b0 + l4*4 + i)*64 + kcol] = h[i];
  }
}

// ---------------------------------------------------------------------------

extern "C" void kernel_launch(void* const* d_in, const int* in_sizes, int n_in,
                              void* d_out, int out_size, void* d_ws, size_t ws_size,
                              hipStream_t stream) {
  const float* ext  = (const float*)d_in[0];
  const float* obs  = (const float*)d_in[1];
  const float* eps  = (const float*)d_in[2];
  const float* puW1 = (const float*)d_in[3];  const float* pub1 = (const float*)d_in[4];
  const float* puW2 = (const float*)d_in[5];  const float* pub2 = (const float*)d_in[6];
  const float* pxW1 = (const float*)d_in[7];  const float* pxb1 = (const float*)d_in[8];
  const float* pxW2 = (const float*)d_in[9];  const float* pxb2 = (const float*)d_in[10];
  const float* pzW1 = (const float*)d_in[11]; const float* pzb1 = (const float*)d_in[12];
  const float* pzW2 = (const float*)d_in[13]; const float* pzb2 = (const float*)d_in[14];
  const float* poW1 = (const float*)d_in[15]; const float* pob1 = (const float*)d_in[16];
  const float* poW2 = (const float*)d_in[17]; const float* pob2 = (const float*)d_in[18];
  const float* poWmu= (const float*)d_in[19]; const float* pobmu= (const float*)d_in[20];
  const float* poWls= (const float*)d_in[21]; const float* pobls= (const float*)d_in[22];
  const float* iWih = (const float*)d_in[23]; const float* iWhh = (const float*)d_in[24];
  const float* ibih = (const float*)d_in[25]; const float* ibhh = (const float*)d_in[26];
  const float* gWih = (const float*)d_in[27]; const float* gWhh = (const float*)d_in[28];
  const float* gbih = (const float*)d_in[29]; const float* gbhh = (const float*)d_in[30];

  float* out = (float*)d_out;
  const size_t OFF_MU   = 0;
  const size_t OFF_LS   = (size_t)LB*32;
  const size_t OFF_S    = (size_t)LB*64;
  const size_t OFF_HSEQ = (size_t)LB*96;
  const size_t OFF_XEMB = (size_t)LB*96 + (size_t)LB*64;
  const size_t OFF_HN   = OFF_XEMB + (size_t)LB*64;

  u16* gen_in = (u16*)d_ws;                          // [LB][128] bf16 (z | u)
  u16* dseq   = (u16*)(out + OFF_HSEQ);              // bf16 park, 1st half of hseq region
  u16* xemb16 = (u16*)(out + OFF_HSEQ + (size_t)LB*32);  // bf16 park, 2nd half

  const int NT = LB/64;

  // u_emb -> gen_in cols 64..127
  k_preprocess<<<NT, 256, 0, stream>>>(ext, puW1, pub1, puW2, pub2, gen_in, 128, 64, nullptr);
  // x_emb -> fp32 output + bf16 park for the inf scan
  k_preprocess<<<NT, 256, 0, stream>>>(obs, pxW1, pxb1, pxW2, pxb2, xemb16, 64, 0, out + OFF_XEMB);
  // inference GRU scan -> d_seq (bf16 park)
  k_scan<false><<<64, 256, 0, stream>>>(xemb16, iWih, iWhh, ibih, ibhh,
                                        dseq, nullptr, nullptr);
  // posterior + sample
  k_posterior<<<NT, 256, 0, stream>>>(dseq, eps, poW1, pob1, poW2, pob2,
                                      poWmu, pobmu, poWls, pobls,
                                      out + OFF_MU, out + OFF_LS, out + OFF_S);
  // z_emb -> gen_in cols 0..63
  k_preprocess<<<NT, 256, 0, stream>>>(out + OFF_S, pzW1, pzb1, pzW2, pzb2, gen_in, 128, 0, nullptr);
  // generative GRU scan -> h_seq, hn
  k_scan<true><<<64, 256, 0, stream>>>(gen_in, gWih, gWhh, gbih, gbhh,
                                       nullptr, out + OFF_HSEQ, out + OFF_HN);
}

// Round 4
// 962.190 us; speedup vs baseline: 1.4743x; 1.0854x over previous
//
#include <hip/hip_runtime.h>

#define L_T 512
#define BATCH 1024
#define LB (L_T*BATCH)
#define NT (LB/64)

typedef short bf16x8 __attribute__((ext_vector_type(8)));
typedef float f32x4 __attribute__((ext_vector_type(4)));
typedef unsigned short u16;

#define MFMA_B16(a,b,c) __builtin_amdgcn_mfma_f32_16x16x32_bf16((a),(b),(c),0,0,0)

__device__ __forceinline__ short f2bs(float f){
  union{float f; unsigned u;} c; c.f=f;
  unsigned r = (c.u + 0x7FFFu + ((c.u>>16)&1u)) >> 16;
  return (short)r;
}

__device__ __forceinline__ unsigned cvtpk(float lo, float hi){
  unsigned d;
  asm("v_cvt_pk_bf16_f32 %0, %1, %2" : "=v"(d) : "v"(lo), "v"(hi));
  return d;
}

__device__ __forceinline__ float sigmoidf_(float x){ return 1.0f/(1.0f + __expf(-x)); }
__device__ __forceinline__ float tanhf_(float x){ return 1.0f - 2.0f/(1.0f + __expf(2.0f*x)); }

__device__ __forceinline__ void store8(u16* d, float4 a, float4 b){
  bf16x8 v;
  v[0]=f2bs(a.x); v[1]=f2bs(a.y); v[2]=f2bs(a.z); v[3]=f2bs(a.w);
  v[4]=f2bs(b.x); v[5]=f2bs(b.y); v[6]=f2bs(b.z); v[7]=f2bs(b.w);
  *(bf16x8*)d = v;
}

__device__ __forceinline__ bf16x8 bfrag_f32(const float* p){
  float4 a = *(const float4*)p;
  float4 b = *(const float4*)(p+4);
  bf16x8 v;
  v[0]=f2bs(a.x); v[1]=f2bs(a.y); v[2]=f2bs(a.z); v[3]=f2bs(a.w);
  v[4]=f2bs(b.x); v[5]=f2bs(b.y); v[6]=f2bs(b.z); v[7]=f2bs(b.w);
  return v;
}

__device__ __forceinline__ void dma16(const void* g, void* l){
  __builtin_amdgcn_global_load_lds(
      (const __attribute__((address_space(1))) void*)g,
      (__attribute__((address_space(3))) void*)l, 16, 0, 0);
}

// ---------------------------------------------------------------------------
// Preprocess body: out = relu(relu(x@W1.T+b1)@W2.T+b2), Cin=32.
// ---------------------------------------------------------------------------
__device__ __forceinline__ void pre_body(
    int bid,
    const float* __restrict__ src, const float* __restrict__ W1,
    const float* __restrict__ b1, const float* __restrict__ W2,
    const float* __restrict__ b2,
    u16* __restrict__ out_b16, int ostride, int ooff,
    float* __restrict__ out_f32)
{
  __shared__ u16 in_t[64*40];
  __shared__ u16 w1t[64*40];
  __shared__ u16 w2t[64*88];
  __shared__ u16 t1t[64*88];
  __shared__ float lb1[64], lb2[64];

  const int t = threadIdx.x;
  const size_t row0 = (size_t)bid * 64;

  {
    int r = t>>2, q = t&3;
    const float* ps = src + (row0 + r)*32 + q*8;
    store8(in_t + r*40 + q*8, *(const float4*)ps, *(const float4*)(ps+4));
    const float* pw = W1 + r*32 + q*8;
    store8(w1t + r*40 + q*8, *(const float4*)pw, *(const float4*)(pw+4));
    const float* pw2 = W2 + r*64 + q*16;
    store8(w2t + r*88 + q*16,     *(const float4*)pw2,     *(const float4*)(pw2+4));
    store8(w2t + r*88 + q*16 + 8, *(const float4*)(pw2+8), *(const float4*)(pw2+12));
    if (t < 64) lb1[t] = b1[t];
    else if (t < 128) lb2[t-64] = b2[t-64];
  }
  __syncthreads();

  const int lane = t & 63, wave = t >> 6;
  const int l15 = lane & 15, l4 = lane >> 4;
  const int rs = wave*16;

  {
    bf16x8 a = *(const bf16x8*)(in_t + (rs + l15)*40 + l4*8);
    #pragma unroll
    for (int ct = 0; ct < 4; ++ct) {
      f32x4 acc = {0.f,0.f,0.f,0.f};
      bf16x8 bw = *(const bf16x8*)(w1t + (ct*16 + l15)*40 + l4*8);
      acc = MFMA_B16(a, bw, acc);
      float bias = lb1[ct*16 + l15];
      #pragma unroll
      for (int i = 0; i < 4; ++i) {
        float v = fmaxf(acc[i] + bias, 0.f);
        t1t[(rs + l4*4 + i)*88 + ct*16 + l15] = (u16)f2bs(v);
      }
    }
  }
  __syncthreads();

  {
    bf16x8 a0 = *(const bf16x8*)(t1t + (rs + l15)*88 + l4*8);
    bf16x8 a1 = *(const bf16x8*)(t1t + (rs + l15)*88 + 32 + l4*8);
    #pragma unroll
    for (int ct = 0; ct < 4; ++ct) {
      f32x4 acc = {0.f,0.f,0.f,0.f};
      bf16x8 b0 = *(const bf16x8*)(w2t + (ct*16 + l15)*88 + l4*8);
      bf16x8 b1v = *(const bf16x8*)(w2t + (ct*16 + l15)*88 + 32 + l4*8);
      acc = MFMA_B16(a0, b0, acc);
      acc = MFMA_B16(a1, b1v, acc);
      float bias = lb2[ct*16 + l15];
      #pragma unroll
      for (int i = 0; i < 4; ++i) {
        float v = fmaxf(acc[i] + bias, 0.f);
        size_t gr = row0 + rs + l4*4 + i;
        int col = ct*16 + l15;
        if (out_b16) out_b16[gr*(size_t)ostride + ooff + col] = (u16)f2bs(v);
        if (out_f32) out_f32[gr*64 + col] = v;
      }
    }
  }
}

// K1: fused x_emb + u_emb (2*NT blocks)
__global__ __launch_bounds__(256) void k_pre2(
    const float* __restrict__ obs,
    const float* __restrict__ pxW1, const float* __restrict__ pxb1,
    const float* __restrict__ pxW2, const float* __restrict__ pxb2,
    u16* __restrict__ xemb16, float* __restrict__ xembf32,
    const float* __restrict__ ext,
    const float* __restrict__ puW1, const float* __restrict__ pub1,
    const float* __restrict__ puW2, const float* __restrict__ pub2,
    u16* __restrict__ gen_in)
{
  int bid = blockIdx.x;
  if (bid < NT) pre_body(bid, obs, pxW1, pxb1, pxW2, pxb2, xemb16, 64, 0, xembf32);
  else          pre_body(bid - NT, ext, puW1, pub1, puW2, pub2, gen_in, 128, 64, nullptr);
}

// ---------------------------------------------------------------------------
// K2: posterior DBlock + reparam sample + z_emb preprocess (fused).
// ---------------------------------------------------------------------------
__global__ __launch_bounds__(256) void k_posterior_z(
    const u16* __restrict__ dseq,             // [LB][64] bf16
    const float* __restrict__ eps,            // [LB][32]
    const float* __restrict__ W1, const float* __restrict__ b1,
    const float* __restrict__ W2, const float* __restrict__ b2,
    const float* __restrict__ Wmu, const float* __restrict__ bmu,
    const float* __restrict__ Wls, const float* __restrict__ bls,
    const float* __restrict__ zW1, const float* __restrict__ zb1,
    const float* __restrict__ zW2, const float* __restrict__ zb2,
    float* __restrict__ out_mu, float* __restrict__ out_ls, float* __restrict__ out_s,
    u16* __restrict__ gen_in)                 // z_emb -> cols 0..63 of [LB][128]
{
  __shared__ u16 dt[64*88], w1t[64*88], w2t[64*88], tt[64*88], zw2t[64*88];
  __shared__ u16 zw1t[64*40], st[64*40];
  __shared__ u16 wmut[32*88], wlst[32*88];
  __shared__ float lb1[64], lb2[64], lbz1[64], lbz2[64], lbmu[32], lbls[32];

  const int t = threadIdx.x;
  const size_t row0 = (size_t)blockIdx.x * 64;

  {
    int r = t>>2, q = t&3;
    const u16* pd = dseq + (row0 + r)*64 + q*16;
    *(bf16x8*)(dt + r*88 + q*16)     = *(const bf16x8*)pd;
    *(bf16x8*)(dt + r*88 + q*16 + 8) = *(const bf16x8*)(pd + 8);
    const float* p1 = W1 + r*64 + q*16;
    store8(w1t + r*88 + q*16,     *(const float4*)p1,     *(const float4*)(p1+4));
    store8(w1t + r*88 + q*16 + 8, *(const float4*)(p1+8), *(const float4*)(p1+12));
    const float* p2 = W2 + r*64 + q*16;
    store8(w2t + r*88 + q*16,     *(const float4*)p2,     *(const float4*)(p2+4));
    store8(w2t + r*88 + q*16 + 8, *(const float4*)(p2+8), *(const float4*)(p2+12));
    const float* pz2 = zW2 + r*64 + q*16;
    store8(zw2t + r*88 + q*16,     *(const float4*)pz2,     *(const float4*)(pz2+4));
    store8(zw2t + r*88 + q*16 + 8, *(const float4*)(pz2+8), *(const float4*)(pz2+12));
    const float* pz1 = zW1 + r*32 + q*8;
    store8(zw1t + r*40 + q*8, *(const float4*)pz1, *(const float4*)(pz1+4));
    if (t < 128) {
      int r2 = t>>2, q2 = t&3;
      const float* pm = Wmu + r2*64 + q2*16;
      store8(wmut + r2*88 + q2*16,     *(const float4*)pm,     *(const float4*)(pm+4));
      store8(wmut + r2*88 + q2*16 + 8, *(const float4*)(pm+8), *(const float4*)(pm+12));
    } else {
      int t2 = t - 128; int r2 = t2>>2, q2 = t2&3;
      const float* pl = Wls + r2*64 + q2*16;
      store8(wlst + r2*88 + q2*16,     *(const float4*)pl,     *(const float4*)(pl+4));
      store8(wlst + r2*88 + q2*16 + 8, *(const float4*)(pl+8), *(const float4*)(pl+12));
    }
    if (t < 64) { lb1[t] = b1[t]; lbz1[t] = zb1[t]; }
    else if (t < 128) { lb2[t-64] = b2[t-64]; lbz2[t-64] = zb2[t-64]; }
    else if (t < 160) lbmu[t-128] = bmu[t-128];
    else if (t < 192) lbls[t-160] = bls[t-160];
  }
  __syncthreads();

  const int lane = t & 63, wave = t >> 6;
  const int l15 = lane & 15, l4 = lane >> 4;
  const int rs = wave*16;

  // gated hidden
  {
    bf16x8 a0 = *(const bf16x8*)(dt + (rs + l15)*88 + l4*8);
    bf16x8 a1 = *(const bf16x8*)(dt + (rs + l15)*88 + 32 + l4*8);
    #pragma unroll
    for (int ct = 0; ct < 4; ++ct) {
      f32x4 c1 = {0.f,0.f,0.f,0.f}, c2 = {0.f,0.f,0.f,0.f};
      bf16x8 w1a = *(const bf16x8*)(w1t + (ct*16 + l15)*88 + l4*8);
      bf16x8 w1b = *(const bf16x8*)(w1t + (ct*16 + l15)*88 + 32 + l4*8);
      bf16x8 w2a = *(const bf16x8*)(w2t + (ct*16 + l15)*88 + l4*8);
      bf16x8 w2b = *(const bf16x8*)(w2t + (ct*16 + l15)*88 + 32 + l4*8);
      c1 = MFMA_B16(a0, w1a, c1); c1 = MFMA_B16(a1, w1b, c1);
      c2 = MFMA_B16(a0, w2a, c2); c2 = MFMA_B16(a1, w2b, c2);
      float bb1 = lb1[ct*16 + l15], bb2 = lb2[ct*16 + l15];
      #pragma unroll
      for (int i = 0; i < 4; ++i) {
        float tv = fmaxf(c1[i] + bb1, 0.f) * sigmoidf_(c2[i] + bb2);
        tt[(rs + l4*4 + i)*88 + ct*16 + l15] = (u16)f2bs(tv);
      }
    }
  }
  __syncthreads();

  // heads + sample; park s (bf16) in st
  {
    bf16x8 a0 = *(const bf16x8*)(tt + (rs + l15)*88 + l4*8);
    bf16x8 a1 = *(const bf16x8*)(tt + (rs + l15)*88 + 32 + l4*8);
    #pragma unroll
    for (int ct = 0; ct < 2; ++ct) {
      f32x4 cmu = {0.f,0.f,0.f,0.f}, cls = {0.f,0.f,0.f,0.f};
      bf16x8 wma = *(const bf16x8*)(wmut + (ct*16 + l15)*88 + l4*8);
      bf16x8 wmb = *(const bf16x8*)(wmut + (ct*16 + l15)*88 + 32 + l4*8);
      bf16x8 wla = *(const bf16x8*)(wlst + (ct*16 + l15)*88 + l4*8);
      bf16x8 wlb = *(const bf16x8*)(wlst + (ct*16 + l15)*88 + 32 + l4*8);
      cmu = MFMA_B16(a0, wma, cmu); cmu = MFMA_B16(a1, wmb, cmu);
      cls = MFMA_B16(a0, wla, cls); cls = MFMA_B16(a1, wlb, cls);
      float bm = lbmu[ct*16 + l15], bl = lbls[ct*16 + l15];
      #pragma unroll
      for (int i = 0; i < 4; ++i) {
        size_t R = row0 + rs + l4*4 + i;
        int col = ct*16 + l15;
        float mu = cmu[i] + bm;
        float ls = cls[i] + bl;
        float e  = eps[R*32 + col];
        float s  = mu + __expf(0.5f*ls)*e;
        out_mu[R*32 + col] = mu;
        out_ls[R*32 + col] = ls;
        out_s [R*32 + col] = s;
        st[(rs + l4*4 + i)*40 + col] = (u16)f2bs(s);
      }
    }
  }
  __syncthreads();

  // z_emb layer 1: relu(s@zW1.T+zb1) -> dt (reuse, stride 88)
  {
    bf16x8 a = *(const bf16x8*)(st + (rs + l15)*40 + l4*8);
    #pragma unroll
    for (int ct = 0; ct < 4; ++ct) {
      f32x4 acc = {0.f,0.f,0.f,0.f};
      bf16x8 bw = *(const bf16x8*)(zw1t + (ct*16 + l15)*40 + l4*8);
      acc = MFMA_B16(a, bw, acc);
      float bias = lbz1[ct*16 + l15];
      #pragma unroll
      for (int i = 0; i < 4; ++i) {
        float v = fmaxf(acc[i] + bias, 0.f);
        dt[(rs + l4*4 + i)*88 + ct*16 + l15] = (u16)f2bs(v);
      }
    }
  }
  __syncthreads();

  // z_emb layer 2 -> gen_in cols 0..63
  {
    bf16x8 a0 = *(const bf16x8*)(dt + (rs + l15)*88 + l4*8);
    bf16x8 a1 = *(const bf16x8*)(dt + (rs + l15)*88 + 32 + l4*8);
    #pragma unroll
    for (int ct = 0; ct < 4; ++ct) {
      f32x4 acc = {0.f,0.f,0.f,0.f};
      bf16x8 b0 = *(const bf16x8*)(zw2t + (ct*16 + l15)*88 + l4*8);
      bf16x8 b1v = *(const bf16x8*)(zw2t + (ct*16 + l15)*88 + 32 + l4*8);
      acc = MFMA_B16(a0, b0, acc);
      acc = MFMA_B16(a1, b1v, acc);
      float bias = lbz2[ct*16 + l15];
      #pragma unroll
      for (int i = 0; i < 4; ++i) {
        float v = fmaxf(acc[i] + bias, 0.f);
        size_t gr = row0 + rs + l4*4 + i;
        gen_in[gr*128 + ct*16 + l15] = (u16)f2bs(v);
      }
    }
  }
}

// ---------------------------------------------------------------------------
// K3/K4: GRU scan v4 — operand-swapped MFMA (D = W · h^T).
// Lane layout: l15 = batch row, wave w + l4 pick 4 contiguous gate/hidden cols
// (c0 = w*16 + l4*4). Per-lane h[i] = h[batch l15][col c0+i].
//  - weight frags as A-operand (identical bytes to v3's B-frags)
//  - x/h as B-operand (identical ds_read pattern as v3)
//  - publish = 2 cvt_pk + 1 ds_write_b64; dseq = dwordx2; hseq = float4
//  - biases live in persistent f32x4 C-init registers (no per-step movs)
//  - gi (x@Wih) pipelined one step ahead, issued under gh's shadow
//  - x staged by global_load_lds DMA in 8-step chunks, source-swizzled
// ---------------------------------------------------------------------------
template<bool IS_GEN>
__global__ __launch_bounds__(256, 1) void k_scan(
    const u16* __restrict__ xin,              // [LB][CIN] bf16
    const float* __restrict__ Wih,            // [192][CIN]
    const float* __restrict__ Whh,            // [192][64]
    const float* __restrict__ bih, const float* __restrict__ bhh,
    u16* __restrict__ dseq_out,               // inf: bf16 [LB][64]
    float* __restrict__ hseq, float* __restrict__ hn)  // gen
{
  constexpr int CIN  = IS_GEN ? 128 : 64;
  constexpr int KC   = CIN / 32;
  constexpr int SPR  = CIN*2/16;              // 16B slots per row
  constexpr int SLICE_U16 = 16*CIN;
  constexpr int CHUNK_U16 = 8*SLICE_U16;
  constexpr int NCHUNK = L_T/8;
  constexpr int ISSUES_W = (CHUNK_U16*2)/(1024*4);  // per-wave DMA issues
  constexpr int HT_U16 = 16*72;

  __shared__ u16 xchunk[2*CHUNK_U16];
  __shared__ u16 ht[2*HT_U16];

  const int t = threadIdx.x;
  const int lane = t & 63, wave = t >> 6;
  const int l15 = lane & 15, l4 = lane >> 4;
  const int b0 = blockIdx.x * 16;
  const int kcol = wave*16 + l15;             // weight-row index (A-frag lane)
  const int c0   = wave*16 + l4*4;            // this lane's 4 output cols

  // weight fragments (A-operand)
  bf16x8 wihf[3][KC], whhf[3][2];
  #pragma unroll
  for (int g = 0; g < 3; ++g) {
    int grow = g*64 + kcol;
    #pragma unroll
    for (int kc = 0; kc < KC; ++kc)
      wihf[g][kc] = bfrag_f32(Wih + (size_t)grow*CIN + kc*32 + l4*8);
    #pragma unroll
    for (int kc = 0; kc < 2; ++kc)
      whhf[g][kc] = bfrag_f32(Whh + (size_t)grow*64 + kc*32 + l4*8);
  }
  // persistent bias C-init vectors (element i -> col c0+i)
  f32x4 bv0, bv1, bvi, bvh;
  #pragma unroll
  for (int i = 0; i < 4; ++i) {
    bv0[i] = bih[c0+i]        + bhh[c0+i];
    bv1[i] = bih[64 + c0+i]   + bhh[64 + c0+i];
    bvi[i] = bih[128 + c0+i];
    bvh[i] = bhh[128 + c0+i];
  }

  auto issue_chunk = [&](int chunk, int bufi){
    const size_t step0 = (size_t)chunk*8;
    u16* dst0 = xchunk + bufi*CHUNK_U16;
    #pragma unroll
    for (int j = 0; j < ISSUES_W; ++j) {
      int o = (j*4 + wave)*1024;              // byte offset within chunk
      int slot = o/16 + lane;
      int r_all = slot / SPR;
      int q = slot % SPR;
      int slice = r_all >> 4, r = r_all & 15;
      int qs = q ^ (r & 7);
      const u16* g = xin + ((step0 + slice)*BATCH + b0 + r)*CIN + qs*8;
      dma16(g, dst0 + o/2);
    }
  };

  float h[4] = {0.f,0.f,0.f,0.f};
  f32x4 gp0, gp1, gp2;                        // gi accumulators (pipelined)
  issue_chunk(0, 0);

  for (int c = 0; c < NCHUNK; ++c) {
    const int cb = c & 1;
    const u16* xbuf = xchunk + cb*CHUNK_U16;
    #pragma unroll
    for (int sp = 0; sp < 8; ++sp) {
      const int step = c*8 + sp;

      // publish h (pre-update state) to ht[sp&1]; gen also emits hseq
      {
        unsigned plo = cvtpk(h[0], h[1]);
        unsigned phi = cvtpk(h[2], h[3]);
        uint2 pv; pv.x = plo; pv.y = phi;
        *(uint2*)(ht + (sp&1)*HT_U16 + l15*72 + c0) = pv;
        if (IS_GEN) {
          float4 hv; hv.x=h[0]; hv.y=h[1]; hv.z=h[2]; hv.w=h[3];
          *(float4*)(hseq + ((size_t)step*BATCH + b0 + l15)*64 + c0) = hv;
        }
      }

      if (sp == 0) asm volatile("s_waitcnt vmcnt(0)" ::: "memory");
      asm volatile("s_waitcnt lgkmcnt(0)\n\ts_barrier" ::: "memory");

      const u16* htr = ht + (sp&1)*HT_U16 + l15*72;
      bf16x8 ha0 = *(const bf16x8*)(htr + l4*8);
      bf16x8 ha1 = *(const bf16x8*)(htr + 32 + l4*8);

      f32x4 a0, a1, a2;
      if (sp == 0) {
        // boundary: gi for this step inline (new chunk just became readable)
        const u16* xb = xbuf + 0*SLICE_U16 + l15*CIN;
        bf16x8 xa[KC];
        #pragma unroll
        for (int kc = 0; kc < KC; ++kc)
          xa[kc] = *(const bf16x8*)(xb + (((l4 + 4*kc) ^ (l15 & 7)) * 8));
        a0 = bv0; a1 = bv1; a2 = bvi;
        #pragma unroll
        for (int kc = 0; kc < KC; ++kc) {
          a0 = MFMA_B16(wihf[0][kc], xa[kc], a0);
          a1 = MFMA_B16(wihf[1][kc], xa[kc], a1);
          a2 = MFMA_B16(wihf[2][kc], xa[kc], a2);
        }
      } else {
        a0 = gp0; a1 = gp1; a2 = gp2;
      }

      if (sp == 1 && c + 1 < NCHUNK) issue_chunk(c + 1, cb ^ 1);

      // gh chains (critical path): continue r/z from gi; n-hidden separate
      f32x4 g0 = MFMA_B16(whhf[0][0], ha0, a0);
      g0       = MFMA_B16(whhf[0][1], ha1, g0);
      f32x4 g1 = MFMA_B16(whhf[1][0], ha0, a1);
      g1       = MFMA_B16(whhf[1][1], ha1, g1);
      f32x4 gn = MFMA_B16(whhf[2][0], ha0, bvh);
      gn       = MFMA_B16(whhf[2][1], ha1, gn);

      // pipeline gi for step+1 (same chunk) under gh/gate latency
      if (sp < 7) {
        const u16* xb = xbuf + (sp+1)*SLICE_U16 + l15*CIN;
        bf16x8 xn[KC];
        #pragma unroll
        for (int kc = 0; kc < KC; ++kc)
          xn[kc] = *(const bf16x8*)(xb + (((l4 + 4*kc) ^ (l15 & 7)) * 8));
        gp0 = bv0; gp1 = bv1; gp2 = bvi;
        #pragma unroll
        for (int kc = 0; kc < KC; ++kc) {
          gp0 = MFMA_B16(wihf[0][kc], xn[kc], gp0);
          gp1 = MFMA_B16(wihf[1][kc], xn[kc], gp1);
          gp2 = MFMA_B16(wihf[2][kc], xn[kc], gp2);
        }
      }

      // gates
      #pragma unroll
      for (int i = 0; i < 4; ++i) {
        float r = sigmoidf_(g0[i]);
        float z = sigmoidf_(g1[i]);
        float n = tanhf_(a2[i] + r*gn[i]);
        h[i] = z*(h[i] - n) + n;
      }

      if (!IS_GEN) {
        unsigned dlo = cvtpk(h[0], h[1]);
        unsigned dhi = cvtpk(h[2], h[3]);
        uint2 dv; dv.x = dlo; dv.y = dhi;
        *(uint2*)(dseq_out + ((size_t)step*BATCH + b0 + l15)*64 + c0) = dv;
      }
    }
  }

  if (IS_GEN) {
    float4 hv; hv.x=h[0]; hv.y=h[1]; hv.z=h[2]; hv.w=h[3];
    *(float4*)(hn + ((size_t)b0 + l15)*64 + c0) = hv;
  }
}

// ---------------------------------------------------------------------------

extern "C" void kernel_launch(void* const* d_in, const int* in_sizes, int n_in,
                              void* d_out, int out_size, void* d_ws, size_t ws_size,
                              hipStream_t stream) {
  const float* ext  = (const float*)d_in[0];
  const float* obs  = (const float*)d_in[1];
  const float* eps  = (const float*)d_in[2];
  const float* puW1 = (const float*)d_in[3];  const float* pub1 = (const float*)d_in[4];
  const float* puW2 = (const float*)d_in[5];  const float* pub2 = (const float*)d_in[6];
  const float* pxW1 = (const float*)d_in[7];  const float* pxb1 = (const float*)d_in[8];
  const float* pxW2 = (const float*)d_in[9];  const float* pxb2 = (const float*)d_in[10];
  const float* pzW1 = (const float*)d_in[11]; const float* pzb1 = (const float*)d_in[12];
  const float* pzW2 = (const float*)d_in[13]; const float* pzb2 = (const float*)d_in[14];
  const float* poW1 = (const float*)d_in[15]; const float* pob1 = (const float*)d_in[16];
  const float* poW2 = (const float*)d_in[17]; const float* pob2 = (const float*)d_in[18];
  const float* poWmu= (const float*)d_in[19]; const float* pobmu= (const float*)d_in[20];
  const float* poWls= (const float*)d_in[21]; const float* pobls= (const float*)d_in[22];
  const float* iWih = (const float*)d_in[23]; const float* iWhh = (const float*)d_in[24];
  const float* ibih = (const float*)d_in[25]; const float* ibhh = (const float*)d_in[26];
  const float* gWih = (const float*)d_in[27]; const float* gWhh = (const float*)d_in[28];
  const float* gbih = (const float*)d_in[29]; const float* gbhh = (const float*)d_in[30];

  float* out = (float*)d_out;
  const size_t OFF_MU   = 0;
  const size_t OFF_LS   = (size_t)LB*32;
  const size_t OFF_S    = (size_t)LB*64;
  const size_t OFF_HSEQ = (size_t)LB*96;
  const size_t OFF_XEMB = (size_t)LB*96 + (size_t)LB*64;
  const size_t OFF_HN   = OFF_XEMB + (size_t)LB*64;

  u16* gen_in = (u16*)d_ws;                          // [LB][128] bf16 (z | u)
  u16* dseq   = (u16*)(out + OFF_HSEQ);              // bf16 park, 1st half of hseq region
  u16* xemb16 = (u16*)(out + OFF_HSEQ + (size_t)LB*32);  // bf16 park, 2nd half

  // x_emb (fp32 out + bf16 park) and u_emb (gen_in hi) in one dispatch
  k_pre2<<<2*NT, 256, 0, stream>>>(obs, pxW1, pxb1, pxW2, pxb2, xemb16, out + OFF_XEMB,
                                   ext, puW1, pub1, puW2, pub2, gen_in);
  // inference GRU scan -> d_seq (bf16 park)
  k_scan<false><<<64, 256, 0, stream>>>(xemb16, iWih, iWhh, ibih, ibhh,
                                        dseq, nullptr, nullptr);
  // posterior + sample + z_emb (gen_in lo)
  k_posterior_z<<<NT, 256, 0, stream>>>(dseq, eps, poW1, pob1, poW2, pob2,
                                        poWmu, pobmu, poWls, pobls,
                                        pzW1, pzb1, pzW2, pzb2,
                                        out + OFF_MU, out + OFF_LS, out + OFF_S, gen_in);
  // generative GRU scan -> h_seq, hn
  k_scan<true><<<64, 256, 0, stream>>>(gen_in, gWih, gWhh, gbih, gbhh,
                                       nullptr, out + OFF_HSEQ, out + OFF_HN);
}